// Round 1
// baseline (291.244 us; speedup 1.0000x reference)
//
#include <hip/hip_runtime.h>
#include <math.h>

#define NBQ 50
#define S1 51
#define IN_D 64
#define HID 128
#define BSZ 256

// ws layout (floats)
#define WS_CC     0                    // 51
#define WS_STEPS  64                   // 51
#define WS_XMAX   128                  // 1
#define WS_BASE   256                  // 256*128
#define WS_SCAL   (256 + 32768)        // 256
#define WS_OFF    (256 + 32768 + 256)  // 256
#define WS_VAL    (256 + 32768 + 512)  // 256*51 = 13056

// K1: cc[51], steps[51], xmax  (1 block, 256 threads)
__global__ void k1_prep(const float* __restrict__ x, float* __restrict__ ws) {
    __shared__ float s_steps[S1];
    __shared__ float s_red[4];
    int t = threadIdx.x;
    if (t < S1) {
        double st = cos((double)t * M_PI / (double)NBQ);
        s_steps[t] = (float)st;
        ws[WS_STEPS + t] = (float)st;
        double acc = 0.0;
        for (int i = 0; i <= NBQ; ++i) {
            double Wi;
            if (i == 0)       Wi = 1.0;
            else if (i & 1)   Wi = 0.0;
            else              Wi = 2.0 / (1.0 - (double)i * (double)i);
            double lam;
            if (t == 0)  lam = 0.5;
            else         lam = cos((double)i * (double)t * M_PI / (double)NBQ);
            if (t == NBQ) lam *= 0.5;
            lam *= 2.0 / (double)NBQ;
            acc += lam * Wi;
        }
        ws[WS_CC + t] = (float)acc;
    }
    __syncthreads();
    // xmax = max over (b,i) of x[b]*(steps[i]+1)/2, +10
    float xb = x[t];  // t == b (256 threads, B=256)
    float m = -1e30f;
    for (int i = 0; i < S1; ++i)
        m = fmaxf(m, xb * (s_steps[i] + 1.0f) * 0.5f);
    for (int off = 32; off > 0; off >>= 1)
        m = fmaxf(m, __shfl_down(m, off));
    if ((t & 63) == 0) s_red[t >> 6] = m;
    __syncthreads();
    if (t == 0) {
        float mm = fmaxf(fmaxf(s_red[0], s_red[1]), fmaxf(s_red[2], s_red[3]));
        ws[WS_XMAX] = mm + 10.0f;
    }
}

// K2: base[b][n] = ib0[n] + h[b]@iw0[1:,n] ; n-network -> offset/scaling
// grid = 256 blocks (one per b), 128 threads (one per hidden n)
__global__ void k2_prep(const float* __restrict__ h,
                        const float* __restrict__ iw0, const float* __restrict__ ib0,
                        const float* __restrict__ nw0, const float* __restrict__ nb0,
                        const float* __restrict__ nw1, const float* __restrict__ nb1,
                        const float* __restrict__ nw2, const float* __restrict__ nb2,
                        float* __restrict__ ws) {
    int b = blockIdx.x;
    int n = threadIdx.x;  // 0..127
    __shared__ float s_h[IN_D - 1];
    __shared__ float s_o0[HID];
    __shared__ float s_part[4];
    if (n < IN_D - 1) s_h[n] = h[b * (IN_D - 1) + n];
    __syncthreads();
    float accB = ib0[n];
    float acc0 = nb0[n];
    for (int d = 0; d < IN_D - 1; ++d) {
        float hv = s_h[d];
        accB = fmaf(hv, iw0[(1 + d) * HID + n], accB);
        acc0 = fmaf(hv, nw0[d * HID + n], acc0);
    }
    ws[WS_BASE + b * HID + n] = accB;
    s_o0[n] = fmaxf(acc0, 0.0f);
    __syncthreads();
    float acc1 = nb1[n];
    for (int m = 0; m < HID; ++m)
        acc1 = fmaf(s_o0[m], nw1[m * HID + n], acc1);
    float o1 = fmaxf(acc1, 0.0f);
    float p0 = o1 * nw2[n * 2 + 0];
    float p1 = o1 * nw2[n * 2 + 1];
    for (int off = 32; off > 0; off >>= 1) {
        p0 += __shfl_down(p0, off);
        p1 += __shfl_down(p1, off);
    }
    int lane = n & 63, w = n >> 6;
    if (lane == 0) { s_part[w * 2] = p0; s_part[w * 2 + 1] = p1; }
    __syncthreads();
    if (n == 0) {
        ws[WS_OFF + b]  = s_part[0] + s_part[2] + nb2[0];
        ws[WS_SCAL + b] = expf(s_part[1] + s_part[3] + nb2[1]);
    }
}

// K3: main compute. One block per b per group-of-4 i. wave = i within group,
// lane = j. Each thread evaluates one point's 128->128->1 MLP with a1[128]
// in VGPRs; iw1 rows / base[b] / iw0 row0 are wave-uniform -> scalar loads.
__global__ __launch_bounds__(256, 2) void k3_main(
        const float* __restrict__ x,
        const float* __restrict__ iw0,   // row 0 = w0n
        const float* __restrict__ iw1,
        const float* __restrict__ ib1,
        const float* __restrict__ iw2,
        const float* __restrict__ ib2,
        const float* ws) {
    int blk = blockIdx.x;
    int b   = blk / 13;
    int ig  = blk % 13;
    int wave = threadIdx.x >> 6;
    int lane = threadIdx.x & 63;
    int i = ig * 4 + wave;
    if (i >= S1) return;

    float xmax    = ws[WS_XMAX];
    float steps_i = ws[WS_STEPS + i];
    int   j       = (lane < S1) ? lane : (S1 - 1);
    float steps_j = ws[WS_STEPS + j];
    float xb = x[b];
    float t  = xb * (steps_i + 1.0f) * 0.5f;
    float s  = t + (xmax - t) * (steps_j + 1.0f) * 0.5f;

    const float* base = ws + WS_BASE + b * HID;

    float a1[HID];
#pragma unroll
    for (int n = 0; n < HID; ++n) a1[n] = 0.0f;

    for (int m = 0; m < HID; ++m) {
        float a0 = fmaxf(fmaf(s, iw0[m], base[m]), 0.0f);
        const float* w1row = iw1 + m * HID;
#pragma unroll
        for (int n = 0; n < HID; ++n)
            a1[n] = fmaf(w1row[n], a0, a1[n]);
    }

    float z = ib2[0];
#pragma unroll
    for (int n = 0; n < HID; ++n) {
        float v = fmaxf(a1[n] + ib1[n], 0.0f);
        z = fmaf(v, iw2[n], z);
    }
    float f = (z > 0.0f) ? (z + 1.0f) : __expf(z);  // elu(z)+1

    float ccj = (lane < S1) ? ws[WS_CC + lane] : 0.0f;
    float val = ccj * f;
    for (int off = 32; off > 0; off >>= 1)
        val += __shfl_down(val, off);
    if (lane == 0) {
        float cci = ws[WS_CC + i];
        float* wsv = (float*)ws;
        wsv[WS_VAL + b * S1 + i] = val * cci * (xmax - t) * 0.5f;
    }
}

// K4: out[b] = scaling[b] * (sum_i val) * x[b]/2 + offset[b]
__global__ void k4_final(const float* __restrict__ x, const float* __restrict__ ws,
                         float* __restrict__ out) {
    int b = threadIdx.x;
    float sum = 0.0f;
    for (int i = 0; i < S1; ++i) sum += ws[WS_VAL + b * S1 + i];
    out[b] = ws[WS_SCAL + b] * sum * x[b] * 0.5f + ws[WS_OFF + b];
}

extern "C" void kernel_launch(void* const* d_in, const int* in_sizes, int n_in,
                              void* d_out, int out_size, void* d_ws, size_t ws_size,
                              hipStream_t stream) {
    const float* x   = (const float*)d_in[0];
    const float* h   = (const float*)d_in[1];
    const float* iw0 = (const float*)d_in[2];
    const float* ib0 = (const float*)d_in[3];
    const float* iw1 = (const float*)d_in[4];
    const float* ib1 = (const float*)d_in[5];
    const float* iw2 = (const float*)d_in[6];
    const float* ib2 = (const float*)d_in[7];
    const float* nw0 = (const float*)d_in[8];
    const float* nb0 = (const float*)d_in[9];
    const float* nw1 = (const float*)d_in[10];
    const float* nb1 = (const float*)d_in[11];
    const float* nw2 = (const float*)d_in[12];
    const float* nb2 = (const float*)d_in[13];
    float* ws  = (float*)d_ws;
    float* out = (float*)d_out;

    hipLaunchKernelGGL(k1_prep, dim3(1), dim3(256), 0, stream, x, ws);
    hipLaunchKernelGGL(k2_prep, dim3(BSZ), dim3(HID), 0, stream,
                       h, iw0, ib0, nw0, nb0, nw1, nb1, nw2, nb2, ws);
    hipLaunchKernelGGL(k3_main, dim3(BSZ * 13), dim3(256), 0, stream,
                       x, iw0, iw1, ib1, iw2, ib2, ws);
    hipLaunchKernelGGL(k4_final, dim3(1), dim3(BSZ), 0, stream, x, ws, out);
}

// Round 2
// 68.517 us; speedup vs baseline: 4.2507x; 4.2507x over previous
//
#include <hip/hip_runtime.h>
#include <math.h>

#define NBQ 50
#define S1 51
#define IN_D 64
#define HID 128
#define BSZ 256

typedef __bf16 bf16x8 __attribute__((ext_vector_type(8)));
typedef float  f32x4  __attribute__((ext_vector_type(4)));

// ws layout (floats)
#define WS_CC     0                    // 51
#define WS_STEPS  64                   // 51
#define WS_XMAX   128                  // 1
#define WS_BASE   256                  // 256*128 = 32768
#define WS_SCAL   33024                // 256
#define WS_OFF    33280                // 256
#define WS_PART   33536                // 256*4 = 1024
#define WS_W1BF   34560                // 16384 bf16 = 8192 floats
// total 42752 floats ~ 171 KB

// K0: pre-swizzle iw1 (f32 [128][128]) -> bf16 fragments.
// frag element order: idx = ((nt*4+kk)*64 + lane)*8 + e
//   <- iw1[ (kk*32 + (lane>>4)*8 + e) * 128 + nt*16 + (lane&15) ]
__global__ void k0_w1conv(const float* __restrict__ iw1, float* __restrict__ ws) {
    int idx = blockIdx.x * 256 + threadIdx.x;   // 0..16383
    int e    = idx & 7;
    int lane = (idx >> 3) & 63;
    int fk   = idx >> 9;          // 0..31
    int kk   = fk & 3;
    int nt   = fk >> 2;
    int k = kk * 32 + (lane >> 4) * 8 + e;
    int n = nt * 16 + (lane & 15);
    __bf16* w1bf = (__bf16*)(ws + WS_W1BF);
    w1bf[idx] = (__bf16)iw1[k * HID + n];
}

// K1: cc[51], steps[51], xmax  (1 block, 256 threads)
__global__ void k1_prep(const float* __restrict__ x, float* __restrict__ ws) {
    __shared__ float s_steps[S1];
    __shared__ float s_red[4];
    int t = threadIdx.x;
    if (t < S1) {
        double st = cos((double)t * M_PI / (double)NBQ);
        s_steps[t] = (float)st;
        ws[WS_STEPS + t] = (float)st;
        double acc = 0.0;
        for (int i = 0; i <= NBQ; ++i) {
            double Wi;
            if (i == 0)       Wi = 1.0;
            else if (i & 1)   Wi = 0.0;
            else              Wi = 2.0 / (1.0 - (double)i * (double)i);
            double lam;
            if (t == 0)  lam = 0.5;
            else         lam = cos((double)i * (double)t * M_PI / (double)NBQ);
            if (t == NBQ) lam *= 0.5;
            lam *= 2.0 / (double)NBQ;
            acc += lam * Wi;
        }
        ws[WS_CC + t] = (float)acc;
    }
    __syncthreads();
    float xb = x[t];
    float m = -1e30f;
    for (int i = 0; i < S1; ++i)
        m = fmaxf(m, xb * (s_steps[i] + 1.0f) * 0.5f);
    for (int off = 32; off > 0; off >>= 1)
        m = fmaxf(m, __shfl_down(m, off));
    if ((t & 63) == 0) s_red[t >> 6] = m;
    __syncthreads();
    if (t == 0) {
        float mm = fmaxf(fmaxf(s_red[0], s_red[1]), fmaxf(s_red[2], s_red[3]));
        ws[WS_XMAX] = mm + 10.0f;
    }
}

// K2: base[b][n] = ib0[n] + h[b]@iw0[1:,n] ; n-network -> offset/scaling
__global__ void k2_prep(const float* __restrict__ h,
                        const float* __restrict__ iw0, const float* __restrict__ ib0,
                        const float* __restrict__ nw0, const float* __restrict__ nb0,
                        const float* __restrict__ nw1, const float* __restrict__ nb1,
                        const float* __restrict__ nw2, const float* __restrict__ nb2,
                        float* __restrict__ ws) {
    int b = blockIdx.x;
    int n = threadIdx.x;  // 0..127
    __shared__ float s_h[IN_D - 1];
    __shared__ float s_o0[HID];
    __shared__ float s_part[4];
    if (n < IN_D - 1) s_h[n] = h[b * (IN_D - 1) + n];
    __syncthreads();
    float accB = ib0[n];
    float acc0 = nb0[n];
    for (int d = 0; d < IN_D - 1; ++d) {
        float hv = s_h[d];
        accB = fmaf(hv, iw0[(1 + d) * HID + n], accB);
        acc0 = fmaf(hv, nw0[d * HID + n], acc0);
    }
    ws[WS_BASE + b * HID + n] = accB;
    s_o0[n] = fmaxf(acc0, 0.0f);
    __syncthreads();
    float acc1 = nb1[n];
    for (int m = 0; m < HID; ++m)
        acc1 = fmaf(s_o0[m], nw1[m * HID + n], acc1);
    float o1 = fmaxf(acc1, 0.0f);
    float p0 = o1 * nw2[n * 2 + 0];
    float p1 = o1 * nw2[n * 2 + 1];
    for (int off = 32; off > 0; off >>= 1) {
        p0 += __shfl_down(p0, off);
        p1 += __shfl_down(p1, off);
    }
    int lane = n & 63, w = n >> 6;
    if (lane == 0) { s_part[w * 2] = p0; s_part[w * 2 + 1] = p1; }
    __syncthreads();
    if (n == 0) {
        ws[WS_OFF + b]  = s_part[0] + s_part[2] + nb2[0];
        ws[WS_SCAL + b] = expf(s_part[1] + s_part[3] + nb2[1]);
    }
}

// K3: MFMA main. block = (b, i-chunk of 13). 4 waves; wave owns 16-point tiles.
// W1 entirely in VGPRs per wave; A built on the fly; layer2+elu+quadrature fused.
__global__ __launch_bounds__(256, 2) void k3_mfma(
        const float* __restrict__ x,
        const float* __restrict__ iw0,   // row 0 = w0 (128 floats)
        const float* __restrict__ ib1,
        const float* __restrict__ iw2,
        const float* __restrict__ ib2,
        float* __restrict__ ws) {
    __shared__ float s_cc[S1];
    __shared__ float s_steps[S1];
    __shared__ float s_inner[16];

    int blk = blockIdx.x;
    int b   = blk >> 2;
    int c   = blk & 3;
    int i0  = c * 13;
    int ni  = (c == 3) ? 12 : 13;
    int npts = ni * S1;                 // 663 or 612
    int ntiles = (npts + 15) >> 4;      // 42 or 39

    int tid  = threadIdx.x;
    int wave = tid >> 6;
    int lane = tid & 63;
    int col  = lane & 15;
    int g    = lane >> 4;

    if (tid < S1) { s_cc[tid] = ws[WS_CC + tid]; s_steps[tid] = ws[WS_STEPS + tid]; }
    if (tid < 16) s_inner[tid] = 0.0f;

    float xmax = ws[WS_XMAX];
    float xb   = x[b];
    float b2   = ib2[0];

    // per-lane W1 fragments: 8 ntiles x 4 ksteps x 8 bf16 = 128 VGPRs
    const bf16x8* w1f = (const bf16x8*)(ws + WS_W1BF);
    bf16x8 Bf[8][4];
#pragma unroll
    for (int nt = 0; nt < 8; ++nt)
#pragma unroll
        for (int kk = 0; kk < 4; ++kk)
            Bf[nt][kk] = w1f[(nt * 4 + kk) * 64 + lane];

    // per-lane w0/base (m = kk*32 + g*8 + e, tile-invariant): 64 VGPRs
    const float* basep = ws + WS_BASE + b * HID;
    f32x4 w0a[4], w0b[4], bsa[4], bsb[4];
#pragma unroll
    for (int kk = 0; kk < 4; ++kk) {
        int m0 = kk * 32 + g * 8;
        w0a[kk] = *(const f32x4*)(iw0 + m0);
        w0b[kk] = *(const f32x4*)(iw0 + m0 + 4);
        bsa[kk] = *(const f32x4*)(basep + m0);
        bsb[kk] = *(const f32x4*)(basep + m0 + 4);
    }
    // per-lane ib1/iw2 (n = nt*16 + col): 16 VGPRs
    float ib1v[8], iw2v[8];
#pragma unroll
    for (int nt = 0; nt < 8; ++nt) {
        ib1v[nt] = ib1[nt * 16 + col];
        iw2v[nt] = iw2[nt * 16 + col];
    }

    __syncthreads();

    for (int tt = wave; tt < ntiles; tt += 4) {
        int p0 = tt * 16;
        int p  = p0 + col;                 // this lane's point (row of A)
        int pe = (p < npts) ? p : (npts - 1);
        int il = pe / S1;
        int jj = pe - il * S1;
        float st_i = s_steps[i0 + il];
        float t_i  = xb * (st_i + 1.0f) * 0.5f;
        float s    = fmaf(xmax - t_i, (s_steps[jj] + 1.0f) * 0.5f, t_i);

        f32x4 acc[8];
#pragma unroll
        for (int nt = 0; nt < 8; ++nt) acc[nt] = (f32x4){0.f, 0.f, 0.f, 0.f};

#pragma unroll
        for (int kk = 0; kk < 4; ++kk) {
            bf16x8 af;
#pragma unroll
            for (int e = 0; e < 4; ++e)
                af[e] = (__bf16)fmaxf(fmaf(s, w0a[kk][e], bsa[kk][e]), 0.0f);
#pragma unroll
            for (int e = 0; e < 4; ++e)
                af[4 + e] = (__bf16)fmaxf(fmaf(s, w0b[kk][e], bsb[kk][e]), 0.0f);
#pragma unroll
            for (int nt = 0; nt < 8; ++nt)
                acc[nt] = __builtin_amdgcn_mfma_f32_16x16x32_bf16(af, Bf[nt][kk], acc[nt], 0, 0, 0);
        }

        // layer2: z[q] for rows r = g*4+q (C layout: row=(lane>>4)*4+reg, col=lane&15)
        f32x4 zv = (f32x4){0.f, 0.f, 0.f, 0.f};
#pragma unroll
        for (int nt = 0; nt < 8; ++nt) {
#pragma unroll
            for (int q = 0; q < 4; ++q) {
                float v = fmaxf(acc[nt][q] + ib1v[nt], 0.0f);
                zv[q] = fmaf(v, iw2v[nt], zv[q]);
            }
        }
#pragma unroll
        for (int q = 0; q < 4; ++q) {
            zv[q] += __shfl_xor(zv[q], 1);
            zv[q] += __shfl_xor(zv[q], 2);
            zv[q] += __shfl_xor(zv[q], 4);
            zv[q] += __shfl_xor(zv[q], 8);
        }
        if (col == 0) {
#pragma unroll
            for (int q = 0; q < 4; ++q) {
                int pq = p0 + g * 4 + q;
                if (pq < npts) {
                    float z = zv[q] + b2;
                    float f = (z > 0.0f) ? (z + 1.0f) : __expf(z);
                    int ilq = pq / S1;
                    int jq  = pq - ilq * S1;
                    atomicAdd(&s_inner[ilq], s_cc[jq] * f);
                }
            }
        }
    }

    __syncthreads();
    if (tid < ni) {
        int i = i0 + tid;
        float t_i = xb * (s_steps[i] + 1.0f) * 0.5f;
        s_inner[tid] = s_inner[tid] * s_cc[i] * (xmax - t_i) * 0.5f;
    }
    __syncthreads();
    if (tid == 0) {
        float sum = 0.0f;
        for (int k = 0; k < ni; ++k) sum += s_inner[k];
        ws[WS_PART + b * 4 + c] = sum;
    }
}

// K4: out[b] = scaling[b] * (sum_c part) * x[b]/2 + offset[b]
__global__ void k4_final(const float* __restrict__ x, const float* __restrict__ ws,
                         float* __restrict__ out) {
    int b = threadIdx.x;
    float sum = ws[WS_PART + b * 4 + 0] + ws[WS_PART + b * 4 + 1]
              + ws[WS_PART + b * 4 + 2] + ws[WS_PART + b * 4 + 3];
    out[b] = ws[WS_SCAL + b] * sum * x[b] * 0.5f + ws[WS_OFF + b];
}

extern "C" void kernel_launch(void* const* d_in, const int* in_sizes, int n_in,
                              void* d_out, int out_size, void* d_ws, size_t ws_size,
                              hipStream_t stream) {
    const float* x   = (const float*)d_in[0];
    const float* h   = (const float*)d_in[1];
    const float* iw0 = (const float*)d_in[2];
    const float* ib0 = (const float*)d_in[3];
    const float* iw1 = (const float*)d_in[4];
    const float* ib1 = (const float*)d_in[5];
    const float* iw2 = (const float*)d_in[6];
    const float* ib2 = (const float*)d_in[7];
    const float* nw0 = (const float*)d_in[8];
    const float* nb0 = (const float*)d_in[9];
    const float* nw1 = (const float*)d_in[10];
    const float* nb1 = (const float*)d_in[11];
    const float* nw2 = (const float*)d_in[12];
    const float* nb2 = (const float*)d_in[13];
    float* ws  = (float*)d_ws;
    float* out = (float*)d_out;

    hipLaunchKernelGGL(k0_w1conv, dim3(64), dim3(256), 0, stream, iw1, ws);
    hipLaunchKernelGGL(k1_prep, dim3(1), dim3(256), 0, stream, x, ws);
    hipLaunchKernelGGL(k2_prep, dim3(BSZ), dim3(HID), 0, stream,
                       h, iw0, ib0, nw0, nb0, nw1, nb1, nw2, nb2, ws);
    hipLaunchKernelGGL(k3_mfma, dim3(BSZ * 4), dim3(256), 0, stream,
                       x, iw0, ib1, iw2, ib2, ws);
    hipLaunchKernelGGL(k4_final, dim3(1), dim3(BSZ), 0, stream, x, ws, out);
}

// Round 3
// 57.554 us; speedup vs baseline: 5.0604x; 1.1905x over previous
//
#include <hip/hip_runtime.h>
#include <math.h>

#define NBQ 50
#define S1 51
#define NPTS 2601      // 51*51
#define NTILES 163     // ceil(2601/16)
#define IN_D 64
#define HID 128
#define BSZ 256
#define NCHUNK 8

typedef __bf16 bf16x8 __attribute__((ext_vector_type(8)));
typedef float  f32x4  __attribute__((ext_vector_type(4)));

// ws layout (floats)
#define WS_CC     0                    // 51
#define WS_STEPS  64                   // 51
#define WS_XMAX   128                  // 1
#define WS_BASE   256                  // 256*128 = 32768
#define WS_SCAL   33024                // 256
#define WS_OFF    33280                // 256
#define WS_PART   33536                // 2048 (256 b * 8 chunks)
#define WS_W1BF   35840                // 16384 bf16 = 8192 floats
// total 44032 floats = 176 KB

// ---------------- prep: w1 fragment conversion + cc/steps/xmax + base + n-net
// blocks 0..63   : convert iw1 -> bf16 A-fragments
// block  64      : cc[51], steps[51], xmax
// blocks 65..320 : base[b] = ib0 + h[b]@iw0[1:], n-network -> offset/scaling
__global__ void k_prep(const float* __restrict__ x, const float* __restrict__ h,
                       const float* __restrict__ iw0, const float* __restrict__ ib0,
                       const float* __restrict__ iw1,
                       const float* __restrict__ nw0, const float* __restrict__ nb0,
                       const float* __restrict__ nw1, const float* __restrict__ nb1,
                       const float* __restrict__ nw2, const float* __restrict__ nb2,
                       float* __restrict__ ws) {
    int blk = blockIdx.x;
    int tid = threadIdx.x;

    if (blk < 64) {
        // A-frag order: idx = ((nt*4+kk)*64 + lane)*8 + e
        //  value = iw1[(kk*32 + (lane>>4)*8 + e)*128 + nt*16 + (lane&15)]
        int idx  = blk * 256 + tid;      // 0..16383
        int e    = idx & 7;
        int lane = (idx >> 3) & 63;
        int fk   = idx >> 9;             // 0..31
        int kk   = fk & 3;
        int nt   = fk >> 2;
        int k = kk * 32 + (lane >> 4) * 8 + e;
        int n = nt * 16 + (lane & 15);
        __bf16* w1bf = (__bf16*)(ws + WS_W1BF);
        w1bf[idx] = (__bf16)iw1[k * HID + n];
        return;
    }

    __shared__ float s_steps[S1];
    __shared__ float s_red[4];
    __shared__ float s_h[IN_D - 1];
    __shared__ float s_o0[HID];
    __shared__ float s_part[4];

    if (blk == 64) {
        int t = tid;
        if (t < S1) {
            double st = cos((double)t * M_PI / (double)NBQ);
            s_steps[t] = (float)st;
            ws[WS_STEPS + t] = (float)st;
            double acc = 0.0;
            for (int i = 0; i <= NBQ; ++i) {
                double Wi;
                if (i == 0)       Wi = 1.0;
                else if (i & 1)   Wi = 0.0;
                else              Wi = 2.0 / (1.0 - (double)i * (double)i);
                double lam;
                if (t == 0)  lam = 0.5;
                else         lam = cos((double)i * (double)t * M_PI / (double)NBQ);
                if (t == NBQ) lam *= 0.5;
                lam *= 2.0 / (double)NBQ;
                acc += lam * Wi;
            }
            ws[WS_CC + t] = (float)acc;
        }
        __syncthreads();
        float xb = x[t];
        float m = -1e30f;
        for (int i = 0; i < S1; ++i)
            m = fmaxf(m, xb * (s_steps[i] + 1.0f) * 0.5f);
        for (int off = 32; off > 0; off >>= 1)
            m = fmaxf(m, __shfl_down(m, off));
        if ((t & 63) == 0) s_red[t >> 6] = m;
        __syncthreads();
        if (t == 0) {
            float mm = fmaxf(fmaxf(s_red[0], s_red[1]), fmaxf(s_red[2], s_red[3]));
            ws[WS_XMAX] = mm + 10.0f;
        }
        return;
    }

    // ---- k2 body: b = blk - 65, first 128 threads active ----
    int b = blk - 65;
    int n = tid;
    bool act = (n < HID);
    if (act && n < IN_D - 1) s_h[n] = h[b * (IN_D - 1) + n];
    __syncthreads();
    float o1 = 0.0f;
    if (act) {
        float accB = ib0[n];
        float acc0 = nb0[n];
        for (int d = 0; d < IN_D - 1; ++d) {
            float hv = s_h[d];
            accB = fmaf(hv, iw0[(1 + d) * HID + n], accB);
            acc0 = fmaf(hv, nw0[d * HID + n], acc0);
        }
        ws[WS_BASE + b * HID + n] = accB;
        s_o0[n] = fmaxf(acc0, 0.0f);
    }
    __syncthreads();
    if (act) {
        float acc1 = nb1[n];
        for (int m = 0; m < HID; ++m)
            acc1 = fmaf(s_o0[m], nw1[m * HID + n], acc1);
        o1 = fmaxf(acc1, 0.0f);
    }
    float p0 = act ? o1 * nw2[n * 2 + 0] : 0.0f;
    float p1 = act ? o1 * nw2[n * 2 + 1] : 0.0f;
    for (int off = 32; off > 0; off >>= 1) {
        p0 += __shfl_down(p0, off);
        p1 += __shfl_down(p1, off);
    }
    int lane = tid & 63, w = tid >> 6;
    if (lane == 0 && w < 2) { s_part[w * 2] = p0; s_part[w * 2 + 1] = p1; }
    __syncthreads();
    if (tid == 0) {
        ws[WS_OFF + b]  = s_part[0] + s_part[2] + nb2[0];
        ws[WS_SCAL + b] = expf(s_part[1] + s_part[3] + nb2[1]);
    }
}

// ---------------- main MFMA kernel: transposed layout ----------------
// A = W1 fragments (rows = n-tile), B = on-the-fly a0 (cols = 16 points).
// One wave per block; block = (b, chunk); chunk c handles tiles t = c, c+8, ...
// C col = lane&15 = point -> layer2 reduce needs only shfl_xor(16), shfl_xor(32).
__global__ __launch_bounds__(64, 1) void k3_mfma(
        const float* __restrict__ x,
        const float* __restrict__ iw0,   // row 0 = w0 (128 floats)
        const float* __restrict__ ib1,
        const float* __restrict__ iw2,
        const float* __restrict__ ib2,
        float* __restrict__ ws) {
    __shared__ float s_cc[S1];
    __shared__ float s_steps[S1];

    int blk  = blockIdx.x;
    int b    = blk >> 3;
    int c    = blk & 7;
    int lane = threadIdx.x;          // 0..63
    int col  = lane & 15;
    int g    = lane >> 4;

    if (lane < S1) { s_cc[lane] = ws[WS_CC + lane]; s_steps[lane] = ws[WS_STEPS + lane]; }
    __syncthreads();

    float xmax = ws[WS_XMAX];
    float xb   = x[b];
    float b2   = ib2[0];

    // W1 A-fragments: 8 nt x 4 kk x 8 bf16 = 128 regs
    const bf16x8* w1f = (const bf16x8*)(ws + WS_W1BF);
    bf16x8 Af[8][4];
#pragma unroll
    for (int nt = 0; nt < 8; ++nt)
#pragma unroll
        for (int kk = 0; kk < 4; ++kk)
            Af[nt][kk] = w1f[(nt * 4 + kk) * 64 + lane];

    // per-lane w0/base for m = kk*32 + g*8 + e : 64 regs
    const float* basep = ws + WS_BASE + b * HID;
    f32x4 w0a[4], w0b[4], bsa[4], bsb[4];
#pragma unroll
    for (int kk = 0; kk < 4; ++kk) {
        int m0 = kk * 32 + g * 8;
        w0a[kk] = *(const f32x4*)(iw0 + m0);
        w0b[kk] = *(const f32x4*)(iw0 + m0 + 4);
        bsa[kk] = *(const f32x4*)(basep + m0);
        bsb[kk] = *(const f32x4*)(basep + m0 + 4);
    }

    // per-lane ib1 (as MFMA C-init) and iw2, n = nt*16 + g*4 + q : 64 regs
    f32x4 accInit[8], iw2v[8];
#pragma unroll
    for (int nt = 0; nt < 8; ++nt) {
        accInit[nt] = *(const f32x4*)(ib1 + nt * 16 + g * 4);
        iw2v[nt]    = *(const f32x4*)(iw2 + nt * 16 + g * 4);
    }

    float vsum = 0.0f;

    for (int t = c; t < NTILES; t += NCHUNK) {
        int p  = t * 16 + col;
        int pc = (p < NPTS) ? p : (NPTS - 1);
        int i  = (int)(((unsigned)pc * 10281u) >> 19);   // pc / 51
        int j  = pc - i * 51;
        float sti = s_steps[i];
        float stj = s_steps[j];
        float ti  = xb * (sti + 1.0f) * 0.5f;
        float w   = xmax - ti;
        float s   = fmaf(w, (stj + 1.0f) * 0.5f, ti);

        f32x4 acc[8];
        // kk = 0: C-init = ib1 (folds layer-1 bias in for free)
        {
            bf16x8 bfr;
#pragma unroll
            for (int e = 0; e < 4; ++e)
                bfr[e] = (__bf16)fmaxf(fmaf(s, w0a[0][e], bsa[0][e]), 0.0f);
#pragma unroll
            for (int e = 0; e < 4; ++e)
                bfr[4 + e] = (__bf16)fmaxf(fmaf(s, w0b[0][e], bsb[0][e]), 0.0f);
#pragma unroll
            for (int nt = 0; nt < 8; ++nt)
                acc[nt] = __builtin_amdgcn_mfma_f32_16x16x32_bf16(Af[nt][0], bfr, accInit[nt], 0, 0, 0);
        }
#pragma unroll
        for (int kk = 1; kk < 4; ++kk) {
            bf16x8 bfr;
#pragma unroll
            for (int e = 0; e < 4; ++e)
                bfr[e] = (__bf16)fmaxf(fmaf(s, w0a[kk][e], bsa[kk][e]), 0.0f);
#pragma unroll
            for (int e = 0; e < 4; ++e)
                bfr[4 + e] = (__bf16)fmaxf(fmaf(s, w0b[kk][e], bsb[kk][e]), 0.0f);
#pragma unroll
            for (int nt = 0; nt < 8; ++nt)
                acc[nt] = __builtin_amdgcn_mfma_f32_16x16x32_bf16(Af[nt][kk], bfr, acc[nt], 0, 0, 0);
        }

        // layer2 partial: z_part = sum over this lane's 32 n-values
        float z = 0.0f;
#pragma unroll
        for (int nt = 0; nt < 8; ++nt)
#pragma unroll
            for (int q = 0; q < 4; ++q)
                z = fmaf(fmaxf(acc[nt][q], 0.0f), iw2v[nt][q], z);
        // complete over the 4 g-groups (same col = same point)
        z += __shfl_xor(z, 16);
        z += __shfl_xor(z, 32);
        z += b2;
        float f   = (z > 0.0f) ? (z + 1.0f) : __expf(z);  // elu+1
        float val = s_cc[i] * s_cc[j] * w * f;
        vsum += (p < NPTS) ? val : 0.0f;
    }

    // wave reduction; each point counted 4x (g) -> x0.25; inner weight /2 -> x0.125
#pragma unroll
    for (int off = 1; off < 64; off <<= 1)
        vsum += __shfl_xor(vsum, off);
    if (lane == 0)
        ws[WS_PART + blk] = vsum * 0.125f;
}

// ---------------- final: out[b] = scal*(sum parts)*x/2 + off ----------------
__global__ void k4_final(const float* __restrict__ x, const float* __restrict__ ws,
                         float* __restrict__ out) {
    int b = threadIdx.x;
    float sum = 0.0f;
#pragma unroll
    for (int c = 0; c < NCHUNK; ++c) sum += ws[WS_PART + b * NCHUNK + c];
    out[b] = ws[WS_SCAL + b] * sum * x[b] * 0.5f + ws[WS_OFF + b];
}

extern "C" void kernel_launch(void* const* d_in, const int* in_sizes, int n_in,
                              void* d_out, int out_size, void* d_ws, size_t ws_size,
                              hipStream_t stream) {
    const float* x   = (const float*)d_in[0];
    const float* h   = (const float*)d_in[1];
    const float* iw0 = (const float*)d_in[2];
    const float* ib0 = (const float*)d_in[3];
    const float* iw1 = (const float*)d_in[4];
    const float* ib1 = (const float*)d_in[5];
    const float* iw2 = (const float*)d_in[6];
    const float* ib2 = (const float*)d_in[7];
    const float* nw0 = (const float*)d_in[8];
    const float* nb0 = (const float*)d_in[9];
    const float* nw1 = (const float*)d_in[10];
    const float* nb1 = (const float*)d_in[11];
    const float* nw2 = (const float*)d_in[12];
    const float* nb2 = (const float*)d_in[13];
    float* ws  = (float*)d_ws;
    float* out = (float*)d_out;

    hipLaunchKernelGGL(k_prep, dim3(64 + 1 + BSZ), dim3(256), 0, stream,
                       x, h, iw0, ib0, iw1, nw0, nb0, nw1, nb1, nw2, nb2, ws);
    hipLaunchKernelGGL(k3_mfma, dim3(BSZ * NCHUNK), dim3(64), 0, stream,
                       x, iw0, ib1, iw2, ib2, ws);
    hipLaunchKernelGGL(k4_final, dim3(1), dim3(BSZ), 0, stream, x, ws, out);
}

// Round 4
// 53.107 us; speedup vs baseline: 5.4842x; 1.0837x over previous
//
#include <hip/hip_runtime.h>
#include <math.h>

#define NBQ 50
#define S1 51
#define NPTS 2601      // 51*51
#define NTILES 163     // ceil(2601/16)
#define IN_D 64
#define HID 128
#define BSZ 256
#define NCHUNK 8

typedef __bf16 bf16x8 __attribute__((ext_vector_type(8)));
typedef float  f32x4  __attribute__((ext_vector_type(4)));

// ws layout (floats)
#define WS_CC     0                    // 51
#define WS_STEPS  64                   // 51
#define WS_XMAX   128                  // 1
#define WS_BASE   256                  // 256*128 = 32768
#define WS_SCAL   33024                // 256
#define WS_OFF    33280                // 256
#define WS_PART   33536                // 2048 (256 b * 8 chunks)
#define WS_W1BF   35840                // 16384 bf16 = 8192 floats

// ---------------- prep: w1 fragment conversion + cc/steps/xmax + base + n-net
__global__ void k_prep(const float* __restrict__ x, const float* __restrict__ h,
                       const float* __restrict__ iw0, const float* __restrict__ ib0,
                       const float* __restrict__ iw1,
                       const float* __restrict__ nw0, const float* __restrict__ nb0,
                       const float* __restrict__ nw1, const float* __restrict__ nb1,
                       const float* __restrict__ nw2, const float* __restrict__ nb2,
                       float* __restrict__ ws) {
    int blk = blockIdx.x;
    int tid = threadIdx.x;

    if (blk < 64) {
        // A-frag order: idx = ((nt*4+kk)*64 + lane)*8 + e
        //  value = iw1[(kk*32 + (lane>>4)*8 + e)*128 + nt*16 + (lane&15)]
        int idx  = blk * 256 + tid;      // 0..16383
        int e    = idx & 7;
        int lane = (idx >> 3) & 63;
        int fk   = idx >> 9;             // 0..31
        int kk   = fk & 3;
        int nt   = fk >> 2;
        int k = kk * 32 + (lane >> 4) * 8 + e;
        int n = nt * 16 + (lane & 15);
        __bf16* w1bf = (__bf16*)(ws + WS_W1BF);
        w1bf[idx] = (__bf16)iw1[k * HID + n];
        return;
    }

    __shared__ float s_steps[S1];
    __shared__ float s_red[4];
    __shared__ float s_h[IN_D - 1];
    __shared__ float s_o0[HID];
    __shared__ float s_part[4];

    if (blk == 64) {
        int t = tid;
        if (t < S1) {
            double st = cos((double)t * M_PI / (double)NBQ);
            s_steps[t] = (float)st;
            ws[WS_STEPS + t] = (float)st;
            double acc = 0.0;
            for (int i = 0; i <= NBQ; ++i) {
                double Wi;
                if (i == 0)       Wi = 1.0;
                else if (i & 1)   Wi = 0.0;
                else              Wi = 2.0 / (1.0 - (double)i * (double)i);
                double lam;
                if (t == 0)  lam = 0.5;
                else         lam = cos((double)i * (double)t * M_PI / (double)NBQ);
                if (t == NBQ) lam *= 0.5;
                lam *= 2.0 / (double)NBQ;
                acc += lam * Wi;
            }
            ws[WS_CC + t] = (float)acc;
        }
        __syncthreads();
        float xb = x[t];
        float m = -1e30f;
        for (int i = 0; i < S1; ++i)
            m = fmaxf(m, xb * (s_steps[i] + 1.0f) * 0.5f);
        for (int off = 32; off > 0; off >>= 1)
            m = fmaxf(m, __shfl_down(m, off));
        if ((t & 63) == 0) s_red[t >> 6] = m;
        __syncthreads();
        if (t == 0) {
            float mm = fmaxf(fmaxf(s_red[0], s_red[1]), fmaxf(s_red[2], s_red[3]));
            ws[WS_XMAX] = mm + 10.0f;
        }
        return;
    }

    // ---- base[b] + n-network: b = blk - 65, first 128 threads active ----
    int b = blk - 65;
    int n = tid;
    bool act = (n < HID);
    if (act && n < IN_D - 1) s_h[n] = h[b * (IN_D - 1) + n];
    __syncthreads();
    float o1 = 0.0f;
    if (act) {
        float accB = ib0[n];
        float acc0 = nb0[n];
        for (int d = 0; d < IN_D - 1; ++d) {
            float hv = s_h[d];
            accB = fmaf(hv, iw0[(1 + d) * HID + n], accB);
            acc0 = fmaf(hv, nw0[d * HID + n], acc0);
        }
        ws[WS_BASE + b * HID + n] = accB;
        s_o0[n] = fmaxf(acc0, 0.0f);
    }
    __syncthreads();
    if (act) {
        float acc1 = nb1[n];
        for (int m = 0; m < HID; ++m)
            acc1 = fmaf(s_o0[m], nw1[m * HID + n], acc1);
        o1 = fmaxf(acc1, 0.0f);
    }
    float p0 = act ? o1 * nw2[n * 2 + 0] : 0.0f;
    float p1 = act ? o1 * nw2[n * 2 + 1] : 0.0f;
    for (int off = 32; off > 0; off >>= 1) {
        p0 += __shfl_down(p0, off);
        p1 += __shfl_down(p1, off);
    }
    int lane = tid & 63, w = tid >> 6;
    if (lane == 0 && w < 2) { s_part[w * 2] = p0; s_part[w * 2 + 1] = p1; }
    __syncthreads();
    if (tid == 0) {
        ws[WS_OFF + b]  = s_part[0] + s_part[2] + nb2[0];
        ws[WS_SCAL + b] = expf(s_part[1] + s_part[3] + nb2[1]);
    }
}

// ---------------- main MFMA kernel: 2 tiles per iteration for ILP ----------
__global__ __launch_bounds__(64, 1) void k3_mfma(
        const float* __restrict__ x,
        const float* __restrict__ iw0,   // row 0 = w0 (128 floats)
        const float* __restrict__ ib1,
        const float* __restrict__ iw2,
        const float* __restrict__ ib2,
        float* __restrict__ ws) {
    __shared__ float s_cc[S1];
    __shared__ float s_steps[S1];

    int blk  = blockIdx.x;
    int b    = blk >> 3;
    int c    = blk & 7;
    int lane = threadIdx.x;          // 0..63
    int col  = lane & 15;
    int g    = lane >> 4;

    if (lane < S1) { s_cc[lane] = ws[WS_CC + lane]; s_steps[lane] = ws[WS_STEPS + lane]; }
    __syncthreads();

    float xmax = ws[WS_XMAX];
    float xb   = x[b];
    float b2   = ib2[0];

    // W1 A-fragments: 8 nt x 4 kk x 8 bf16 = 128 regs
    const bf16x8* w1f = (const bf16x8*)(ws + WS_W1BF);
    bf16x8 Af[8][4];
#pragma unroll
    for (int nt = 0; nt < 8; ++nt)
#pragma unroll
        for (int kk = 0; kk < 4; ++kk)
            Af[nt][kk] = w1f[(nt * 4 + kk) * 64 + lane];

    // per-lane w0/base for m = kk*32 + g*8 + e : 64 regs
    const float* basep = ws + WS_BASE + b * HID;
    f32x4 w0a[4], w0b[4], bsa[4], bsb[4];
#pragma unroll
    for (int kk = 0; kk < 4; ++kk) {
        int m0 = kk * 32 + g * 8;
        w0a[kk] = *(const f32x4*)(iw0 + m0);
        w0b[kk] = *(const f32x4*)(iw0 + m0 + 4);
        bsa[kk] = *(const f32x4*)(basep + m0);
        bsb[kk] = *(const f32x4*)(basep + m0 + 4);
    }

    // per-lane ib1 (MFMA C-init) and iw2, n = nt*16 + g*4 + q
    f32x4 accInit[8], iw2v[8];
#pragma unroll
    for (int nt = 0; nt < 8; ++nt) {
        accInit[nt] = *(const f32x4*)(ib1 + nt * 16 + g * 4);
        iw2v[nt]    = *(const f32x4*)(iw2 + nt * 16 + g * 4);
    }

    float vsum = 0.0f;

    for (int tt = c; tt < NTILES; tt += 2 * NCHUNK) {
        int t1v = tt + NCHUNK;
        bool v1 = (t1v < NTILES);
        int t1 = v1 ? t1v : tt;

        // ---- per-lane point geometry for both tiles ----
        int p0 = tt * 16 + col;
        int p1 = t1 * 16 + col;
        int pc0 = (p0 < NPTS) ? p0 : (NPTS - 1);
        int pc1 = (p1 < NPTS) ? p1 : (NPTS - 1);
        int i_0 = (int)(((unsigned)pc0 * 10281u) >> 19);   // /51
        int i_1 = (int)(((unsigned)pc1 * 10281u) >> 19);
        int j_0 = pc0 - i_0 * 51;
        int j_1 = pc1 - i_1 * 51;
        float ti0 = xb * (s_steps[i_0] + 1.0f) * 0.5f;
        float ti1 = xb * (s_steps[i_1] + 1.0f) * 0.5f;
        float w_0 = xmax - ti0;
        float w_1 = xmax - ti1;
        float s0 = fmaf(w_0, (s_steps[j_0] + 1.0f) * 0.5f, ti0);
        float s1 = fmaf(w_1, (s_steps[j_1] + 1.0f) * 0.5f, ti1);

        f32x4 acc0[8], acc1[8];

#pragma unroll
        for (int kk = 0; kk < 4; ++kk) {
            bf16x8 bfr0, bfr1;
#pragma unroll
            for (int e = 0; e < 4; ++e) {
                bfr0[e]     = (__bf16)fmaxf(fmaf(s0, w0a[kk][e], bsa[kk][e]), 0.0f);
                bfr0[4 + e] = (__bf16)fmaxf(fmaf(s0, w0b[kk][e], bsb[kk][e]), 0.0f);
                bfr1[e]     = (__bf16)fmaxf(fmaf(s1, w0a[kk][e], bsa[kk][e]), 0.0f);
                bfr1[4 + e] = (__bf16)fmaxf(fmaf(s1, w0b[kk][e], bsb[kk][e]), 0.0f);
            }
#pragma unroll
            for (int nt = 0; nt < 8; ++nt) {
                acc0[nt] = __builtin_amdgcn_mfma_f32_16x16x32_bf16(
                    Af[nt][kk], bfr0, (kk == 0) ? accInit[nt] : acc0[nt], 0, 0, 0);
                acc1[nt] = __builtin_amdgcn_mfma_f32_16x16x32_bf16(
                    Af[nt][kk], bfr1, (kk == 0) ? accInit[nt] : acc1[nt], 0, 0, 0);
            }
        }

        // layer2 partials, split into 2 chains each (depth 16)
        float za0 = 0.f, zb0 = 0.f, za1 = 0.f, zb1 = 0.f;
#pragma unroll
        for (int nt = 0; nt < 4; ++nt)
#pragma unroll
            for (int q = 0; q < 4; ++q) {
                za0 = fmaf(fmaxf(acc0[nt][q], 0.0f), iw2v[nt][q], za0);
                za1 = fmaf(fmaxf(acc1[nt][q], 0.0f), iw2v[nt][q], za1);
            }
#pragma unroll
        for (int nt = 4; nt < 8; ++nt)
#pragma unroll
            for (int q = 0; q < 4; ++q) {
                zb0 = fmaf(fmaxf(acc0[nt][q], 0.0f), iw2v[nt][q], zb0);
                zb1 = fmaf(fmaxf(acc1[nt][q], 0.0f), iw2v[nt][q], zb1);
            }
        float z0 = za0 + zb0;
        float z1 = za1 + zb1;
        z0 += __shfl_xor(z0, 16);
        z1 += __shfl_xor(z1, 16);
        z0 += __shfl_xor(z0, 32);
        z1 += __shfl_xor(z1, 32);
        z0 += b2;
        z1 += b2;
        float f0 = (z0 > 0.0f) ? (z0 + 1.0f) : __expf(z0);
        float f1 = (z1 > 0.0f) ? (z1 + 1.0f) : __expf(z1);
        float val0 = s_cc[i_0] * s_cc[j_0] * w_0 * f0;
        float val1 = s_cc[i_1] * s_cc[j_1] * w_1 * f1;
        vsum += (p0 < NPTS) ? val0 : 0.0f;
        vsum += (v1 && p1 < NPTS) ? val1 : 0.0f;
    }

    // wave reduction; each point counted 4x (g) -> x0.25; inner weight /2 -> x0.125
#pragma unroll
    for (int off = 1; off < 64; off <<= 1)
        vsum += __shfl_xor(vsum, off);
    if (lane == 0)
        ws[WS_PART + blk] = vsum * 0.125f;
}

// ---------------- final: out[b] = scal*(sum parts)*x/2 + off ----------------
__global__ void k4_final(const float* __restrict__ x, const float* __restrict__ ws,
                         float* __restrict__ out) {
    int b = threadIdx.x;
    float sum = 0.0f;
#pragma unroll
    for (int c = 0; c < NCHUNK; ++c) sum += ws[WS_PART + b * NCHUNK + c];
    out[b] = ws[WS_SCAL + b] * sum * x[b] * 0.5f + ws[WS_OFF + b];
}

extern "C" void kernel_launch(void* const* d_in, const int* in_sizes, int n_in,
                              void* d_out, int out_size, void* d_ws, size_t ws_size,
                              hipStream_t stream) {
    const float* x   = (const float*)d_in[0];
    const float* h   = (const float*)d_in[1];
    const float* iw0 = (const float*)d_in[2];
    const float* ib0 = (const float*)d_in[3];
    const float* iw1 = (const float*)d_in[4];
    const float* ib1 = (const float*)d_in[5];
    const float* iw2 = (const float*)d_in[6];
    const float* ib2 = (const float*)d_in[7];
    const float* nw0 = (const float*)d_in[8];
    const float* nb0 = (const float*)d_in[9];
    const float* nw1 = (const float*)d_in[10];
    const float* nb1 = (const float*)d_in[11];
    const float* nw2 = (const float*)d_in[12];
    const float* nb2 = (const float*)d_in[13];
    float* ws  = (float*)d_ws;
    float* out = (float*)d_out;

    hipLaunchKernelGGL(k_prep, dim3(64 + 1 + BSZ), dim3(256), 0, stream,
                       x, h, iw0, ib0, iw1, nw0, nb0, nw1, nb1, nw2, nb2, ws);
    hipLaunchKernelGGL(k3_mfma, dim3(BSZ * NCHUNK), dim3(64), 0, stream,
                       x, iw0, ib1, iw2, ib2, ws);
    hipLaunchKernelGGL(k4_final, dim3(1), dim3(BSZ), 0, stream, x, ws, out);
}